// Round 1
// baseline (158.385 us; speedup 1.0000x reference)
//
#include <hip/hip_runtime.h>

#define NFEAT   100000
#define NBATCH  256
#define DIM     128
#define MARGIN_F 0.5f
#define BN      128
#define NBLK    ((NFEAT + BN - 1) / BN)   // 782
#define FLT_BIG 3.402823466e+38f

typedef __bf16 bf8_t  __attribute__((ext_vector_type(8)));
typedef short  sh8_t  __attribute__((ext_vector_type(8)));
typedef float  f32x4  __attribute__((ext_vector_type(4)));

// --- f32 -> bf16 (round-to-nearest-even), bit-level so no __bf16 arith needed
__device__ __forceinline__ __bf16 f2bf(float f) {
  unsigned u = __builtin_bit_cast(unsigned, f);
  u += 0x7FFFu + ((u >> 16) & 1u);
  unsigned short h = (unsigned short)(u >> 16);
  return __builtin_bit_cast(__bf16, h);
}

__device__ __forceinline__ bf8_t pack8(float4 v0, float4 v1) {
  bf8_t r;
  r[0] = f2bf(v0.x); r[1] = f2bf(v0.y); r[2] = f2bf(v0.z); r[3] = f2bf(v0.w);
  r[4] = f2bf(v1.x); r[5] = f2bf(v1.y); r[6] = f2bf(v1.z); r[7] = f2bf(v1.w);
  return r;
}

// --- MFMA dispatch: works whether the builtin takes bf16-vectors or short-vectors
template <typename VA, typename VC>
__device__ __forceinline__ auto mfma_sel(VA a, VA b, VC c, int)
    -> decltype(__builtin_amdgcn_mfma_f32_16x16x32_bf16(a, b, c, 0, 0, 0)) {
  return __builtin_amdgcn_mfma_f32_16x16x32_bf16(a, b, c, 0, 0, 0);
}
template <typename VA, typename VC>
__device__ __forceinline__ VC mfma_sel(VA a, VA b, VC c, long) {
  return __builtin_amdgcn_mfma_f32_16x16x32_bf16(
      __builtin_bit_cast(sh8_t, a), __builtin_bit_cast(sh8_t, b), c, 0, 0, 0);
}
__device__ __forceinline__ f32x4 mfma_bf16(bf8_t a, bf8_t b, f32x4 c) {
  return mfma_sel(a, b, c, 0);
}

// Kernel 1: fused GEMM + masked min/max partial reduction.
// Block b handles feature cols [b*BN, b*BN+BN). 4 waves; wave w owns batch rows
// [64w, 64w+64). A-frags in VGPRs; B read from global (f32) + inline bf16 cvt.
// MFMA 16x16x32 layouts (guide §3, m89/m91-verified C/D):
//   A: lane l holds A[m0 + (l&15)][k0 + (l>>4)*8 + e], e=0..7
//   B: lane l holds B[k0 + (l>>4)*8 + e][j0 + (l&15)]  (= features[j][k], row-major)
//   D: lane l reg r = sim[m0 + (l>>4)*4 + r][j0 + (l&15)]
__global__ __launch_bounds__(256) void triplet_partial(
    const float* __restrict__ inputs, const float* __restrict__ features,
    const int* __restrict__ targets, const int* __restrict__ flabels,
    const int* __restrict__ idx,
    float* __restrict__ ppos, float* __restrict__ pneg)
{
  const int tid  = threadIdx.x;
  const int lane = tid & 63;
  const int wv   = tid >> 6;      // 0..3
  const int l15  = lane & 15;
  const int lg   = lane >> 4;     // 0..3
  const int m0   = wv * 64;
  const int blk  = blockIdx.x;
  const int jbase = blk * BN;

  // A fragments: [4 M-tiles of 16 rows][4 K-steps of 32]
  bf8_t afrag[4][4];
#pragma unroll
  for (int mt = 0; mt < 4; ++mt) {
    const float* ap = inputs + (m0 + mt * 16 + l15) * DIM;
#pragma unroll
    for (int ks = 0; ks < 4; ++ks) {
      const int k = ks * 32 + lg * 8;
      float4 v0 = *reinterpret_cast<const float4*>(ap + k);
      float4 v1 = *reinterpret_cast<const float4*>(ap + k + 4);
      afrag[mt][ks] = pack8(v0, v1);
    }
  }

  // Per-thread row metadata for the 16 output rows this lane sees
  int tgt[4][4], sidx[4][4];
#pragma unroll
  for (int mt = 0; mt < 4; ++mt)
#pragma unroll
    for (int rr = 0; rr < 4; ++rr) {
      const int row = m0 + mt * 16 + lg * 4 + rr;
      tgt[mt][rr]  = targets[row];
      sidx[mt][rr] = idx[row];
    }

  float minpos[4][4], maxneg[4][4];
#pragma unroll
  for (int mt = 0; mt < 4; ++mt)
#pragma unroll
    for (int rr = 0; rr < 4; ++rr) { minpos[mt][rr] = FLT_BIG; maxneg[mt][rr] = -FLT_BIG; }

  for (int ng = 0; ng < BN / 16; ++ng) {
    const int j = jbase + ng * 16 + l15;
    const bool jvalid = (j < NFEAT);
    const int jc = jvalid ? j : (NFEAT - 1);
    const int labj = flabels[jc];
    const float* fp = features + (long)jc * DIM;

    bf8_t bfrag[4];
#pragma unroll
    for (int ks = 0; ks < 4; ++ks) {
      const int k = ks * 32 + lg * 8;
      float4 v0 = *reinterpret_cast<const float4*>(fp + k);
      float4 v1 = *reinterpret_cast<const float4*>(fp + k + 4);
      bfrag[ks] = pack8(v0, v1);
    }

#pragma unroll
    for (int mt = 0; mt < 4; ++mt) {
      f32x4 acc = {0.f, 0.f, 0.f, 0.f};
#pragma unroll
      for (int ks = 0; ks < 4; ++ks)
        acc = mfma_bf16(afrag[mt][ks], bfrag[ks], acc);
#pragma unroll
      for (int rr = 0; rr < 4; ++rr) {
        const float s   = acc[rr];
        const bool same  = (labj == tgt[mt][rr]);
        const bool posok = jvalid && same && (j != sidx[mt][rr]);
        const bool negok = jvalid && !same;
        minpos[mt][rr] = fminf(minpos[mt][rr], posok ? s :  FLT_BIG);
        maxneg[mt][rr] = fmaxf(maxneg[mt][rr], negok ? s : -FLT_BIG);
      }
    }
  }

  // Reduce over the 16 cols held across each 16-lane group, then write partials
#pragma unroll
  for (int mt = 0; mt < 4; ++mt)
#pragma unroll
    for (int rr = 0; rr < 4; ++rr) {
      float mp = minpos[mt][rr], mn = maxneg[mt][rr];
#pragma unroll
      for (int m = 1; m < 16; m <<= 1) {
        mp = fminf(mp, __shfl_xor(mp, m, 64));
        mn = fmaxf(mn, __shfl_xor(mn, m, 64));
      }
      if (l15 == 0) {
        const int row = m0 + mt * 16 + lg * 4 + rr;
        ppos[blk * NBATCH + row] = mp;
        pneg[blk * NBATCH + row] = mn;
      }
    }
}

// Kernel 2: fold partials across blocks, hinge, mean.
__global__ __launch_bounds__(256) void triplet_final(
    const float* __restrict__ ppos, const float* __restrict__ pneg,
    float* __restrict__ out)
{
  const int i = threadIdx.x;   // one thread per batch row
  float mp = FLT_BIG, mn = -FLT_BIG;
  for (int b = 0; b < NBLK; ++b) {
    mp = fminf(mp, ppos[b * NBATCH + i]);
    mn = fmaxf(mn, pneg[b * NBATCH + i]);
  }
  float loss = mn - mp + MARGIN_F;
  loss = loss > 0.f ? loss : 0.f;
#pragma unroll
  for (int m = 1; m < 64; m <<= 1) loss += __shfl_xor(loss, m, 64);
  __shared__ float red[4];
  if ((i & 63) == 0) red[i >> 6] = loss;
  __syncthreads();
  if (i == 0) out[0] = (red[0] + red[1] + red[2] + red[3]) * (1.0f / NBATCH);
}

extern "C" void kernel_launch(void* const* d_in, const int* in_sizes, int n_in,
                              void* d_out, int out_size, void* d_ws, size_t ws_size,
                              hipStream_t stream) {
  const float* inputs   = (const float*)d_in[0];
  const float* features = (const float*)d_in[1];
  const int*   targets  = (const int*)d_in[2];
  const int*   flabels  = (const int*)d_in[3];
  const int*   idx      = (const int*)d_in[4];
  float* out  = (float*)d_out;
  float* ppos = (float*)d_ws;                 // [NBLK][256]
  float* pneg = ppos + (size_t)NBLK * NBATCH; // [NBLK][256]  (~1.6 MB total)

  triplet_partial<<<NBLK, 256, 0, stream>>>(inputs, features, targets, flabels, idx, ppos, pneg);
  triplet_final<<<1, 256, 0, stream>>>(ppos, pneg, out);
}

// Round 2
// 61.664 us; speedup vs baseline: 2.5685x; 2.5685x over previous
//
#include <hip/hip_runtime.h>

#define NFEAT   100000
#define NBATCH  256
#define DIM     128
#define MARGIN_F 0.5f
#define BN      128
#define NBLK    ((NFEAT + BN - 1) / BN)   // 782
#define FLT_BIG 3.402823466e+38f

typedef __bf16 bf8_t  __attribute__((ext_vector_type(8)));
typedef short  sh8_t  __attribute__((ext_vector_type(8)));
typedef float  f32x4  __attribute__((ext_vector_type(4)));

// --- f32 -> bf16 (round-to-nearest-even), bit-level so no __bf16 arith needed
__device__ __forceinline__ __bf16 f2bf(float f) {
  unsigned u = __builtin_bit_cast(unsigned, f);
  u += 0x7FFFu + ((u >> 16) & 1u);
  unsigned short h = (unsigned short)(u >> 16);
  return __builtin_bit_cast(__bf16, h);
}

__device__ __forceinline__ bf8_t pack8(float4 v0, float4 v1) {
  bf8_t r;
  r[0] = f2bf(v0.x); r[1] = f2bf(v0.y); r[2] = f2bf(v0.z); r[3] = f2bf(v0.w);
  r[4] = f2bf(v1.x); r[5] = f2bf(v1.y); r[6] = f2bf(v1.z); r[7] = f2bf(v1.w);
  return r;
}

// --- MFMA dispatch: works whether the builtin takes bf16-vectors or short-vectors
template <typename VA, typename VC>
__device__ __forceinline__ auto mfma_sel(VA a, VA b, VC c, int)
    -> decltype(__builtin_amdgcn_mfma_f32_16x16x32_bf16(a, b, c, 0, 0, 0)) {
  return __builtin_amdgcn_mfma_f32_16x16x32_bf16(a, b, c, 0, 0, 0);
}
template <typename VA, typename VC>
__device__ __forceinline__ VC mfma_sel(VA a, VA b, VC c, long) {
  return __builtin_amdgcn_mfma_f32_16x16x32_bf16(
      __builtin_bit_cast(sh8_t, a), __builtin_bit_cast(sh8_t, b), c, 0, 0, 0);
}
__device__ __forceinline__ f32x4 mfma_bf16(bf8_t a, bf8_t b, f32x4 c) {
  return mfma_sel(a, b, c, 0);
}

// Kernel 1: fused GEMM + masked min/max partial reduction.
// Block b handles feature cols [b*BN, b*BN+BN). 4 waves; wave w owns batch rows
// [64w, 64w+64). A-frags in VGPRs; B read from global (f32) + inline bf16 cvt.
// MFMA 16x16x32 layouts (guide §3, m89/m91-verified C/D):
//   A: lane l holds A[m0 + (l&15)][k0 + (l>>4)*8 + e], e=0..7
//   B: lane l holds B[k0 + (l>>4)*8 + e][j0 + (l&15)]  (= features[j][k], row-major)
//   D: lane l reg r = sim[m0 + (l>>4)*4 + r][j0 + (l&15)]
// Partials written TRANSPOSED: ppos[row*NBLK + blk] so kernel 2 reads coalesce.
__global__ __launch_bounds__(256) void triplet_partial(
    const float* __restrict__ inputs, const float* __restrict__ features,
    const int* __restrict__ targets, const int* __restrict__ flabels,
    const int* __restrict__ idx,
    float* __restrict__ ppos, float* __restrict__ pneg,
    float* __restrict__ out)
{
  const int tid  = threadIdx.x;
  const int lane = tid & 63;
  const int wv   = tid >> 6;      // 0..3
  const int l15  = lane & 15;
  const int lg   = lane >> 4;     // 0..3
  const int m0   = wv * 64;
  const int blk  = blockIdx.x;
  const int jbase = blk * BN;

  if (blk == 0 && tid == 0) out[0] = 0.0f;   // kernel 2 accumulates atomically

  // A fragments: [4 M-tiles of 16 rows][4 K-steps of 32]
  bf8_t afrag[4][4];
#pragma unroll
  for (int mt = 0; mt < 4; ++mt) {
    const float* ap = inputs + (m0 + mt * 16 + l15) * DIM;
#pragma unroll
    for (int ks = 0; ks < 4; ++ks) {
      const int k = ks * 32 + lg * 8;
      float4 v0 = *reinterpret_cast<const float4*>(ap + k);
      float4 v1 = *reinterpret_cast<const float4*>(ap + k + 4);
      afrag[mt][ks] = pack8(v0, v1);
    }
  }

  // Per-thread row metadata for the 16 output rows this lane sees
  int tgt[4][4], sidx[4][4];
#pragma unroll
  for (int mt = 0; mt < 4; ++mt)
#pragma unroll
    for (int rr = 0; rr < 4; ++rr) {
      const int row = m0 + mt * 16 + lg * 4 + rr;
      tgt[mt][rr]  = targets[row];
      sidx[mt][rr] = idx[row];
    }

  float minpos[4][4], maxneg[4][4];
#pragma unroll
  for (int mt = 0; mt < 4; ++mt)
#pragma unroll
    for (int rr = 0; rr < 4; ++rr) { minpos[mt][rr] = FLT_BIG; maxneg[mt][rr] = -FLT_BIG; }

  for (int ng = 0; ng < BN / 16; ++ng) {
    const int j = jbase + ng * 16 + l15;
    const bool jvalid = (j < NFEAT);
    const int jc = jvalid ? j : (NFEAT - 1);
    const int labj = flabels[jc];
    const float* fp = features + (long)jc * DIM;

    bf8_t bfrag[4];
#pragma unroll
    for (int ks = 0; ks < 4; ++ks) {
      const int k = ks * 32 + lg * 8;
      float4 v0 = *reinterpret_cast<const float4*>(fp + k);
      float4 v1 = *reinterpret_cast<const float4*>(fp + k + 4);
      bfrag[ks] = pack8(v0, v1);
    }

#pragma unroll
    for (int mt = 0; mt < 4; ++mt) {
      f32x4 acc = {0.f, 0.f, 0.f, 0.f};
#pragma unroll
      for (int ks = 0; ks < 4; ++ks)
        acc = mfma_bf16(afrag[mt][ks], bfrag[ks], acc);
#pragma unroll
      for (int rr = 0; rr < 4; ++rr) {
        const float s   = acc[rr];
        const bool same  = (labj == tgt[mt][rr]);
        const bool posok = jvalid && same && (j != sidx[mt][rr]);
        const bool negok = jvalid && !same;
        minpos[mt][rr] = fminf(minpos[mt][rr], posok ? s :  FLT_BIG);
        maxneg[mt][rr] = fmaxf(maxneg[mt][rr], negok ? s : -FLT_BIG);
      }
    }
  }

  // Reduce over the 16 cols held across each 16-lane group, then write partials
#pragma unroll
  for (int mt = 0; mt < 4; ++mt)
#pragma unroll
    for (int rr = 0; rr < 4; ++rr) {
      float mp = minpos[mt][rr], mn = maxneg[mt][rr];
#pragma unroll
      for (int m = 1; m < 16; m <<= 1) {
        mp = fminf(mp, __shfl_xor(mp, m, 64));
        mn = fmaxf(mn, __shfl_xor(mn, m, 64));
      }
      if (l15 == 0) {
        const int row = m0 + mt * 16 + lg * 4 + rr;
        ppos[row * NBLK + blk] = mp;
        pneg[row * NBLK + blk] = mn;
      }
    }
}

// Kernel 2: one block per batch row. Coalesced fold of the NBLK partials,
// block-wide min/max reduce, hinge, atomic mean-accumulate into out[0].
__global__ __launch_bounds__(256) void triplet_reduce(
    const float* __restrict__ ppos, const float* __restrict__ pneg,
    float* __restrict__ out)
{
  const int r = blockIdx.x;
  const int t = threadIdx.x;
  float mp = FLT_BIG, mn = -FLT_BIG;
  for (int b = t; b < NBLK; b += 256) {
    mp = fminf(mp, ppos[r * NBLK + b]);
    mn = fmaxf(mn, pneg[r * NBLK + b]);
  }
#pragma unroll
  for (int m = 1; m < 64; m <<= 1) {
    mp = fminf(mp, __shfl_xor(mp, m, 64));
    mn = fmaxf(mn, __shfl_xor(mn, m, 64));
  }
  __shared__ float smp[4], smn[4];
  if ((t & 63) == 0) { smp[t >> 6] = mp; smn[t >> 6] = mn; }
  __syncthreads();
  if (t == 0) {
    mp = fminf(fminf(smp[0], smp[1]), fminf(smp[2], smp[3]));
    mn = fmaxf(fmaxf(smn[0], smn[1]), fmaxf(smn[2], smn[3]));
    float loss = mn - mp + MARGIN_F;
    loss = loss > 0.f ? loss : 0.f;
    atomicAdd(out, loss * (1.0f / NBATCH));
  }
}

extern "C" void kernel_launch(void* const* d_in, const int* in_sizes, int n_in,
                              void* d_out, int out_size, void* d_ws, size_t ws_size,
                              hipStream_t stream) {
  const float* inputs   = (const float*)d_in[0];
  const float* features = (const float*)d_in[1];
  const int*   targets  = (const int*)d_in[2];
  const int*   flabels  = (const int*)d_in[3];
  const int*   idx      = (const int*)d_in[4];
  float* out  = (float*)d_out;
  float* ppos = (float*)d_ws;                 // [256][NBLK]
  float* pneg = ppos + (size_t)NBLK * NBATCH; // [256][NBLK]  (~1.6 MB total)

  triplet_partial<<<NBLK, 256, 0, stream>>>(inputs, features, targets, flabels, idx, ppos, pneg, out);
  triplet_reduce<<<NBATCH, 256, 0, stream>>>(ppos, pneg, out);
}